// Round 1
// baseline (210.227 us; speedup 1.0000x reference)
//
#include <hip/hip_runtime.h>
#include <hip/hip_bf16.h>
#include <math.h>

#define MARGIN_C 0.3f
#define CLST_SCALE 0.8f
#define SEP_SCALE 0.08f
#define DIV_SCALE 0.01f
#define CONTRASTIVE_SCALE 0.1f

#define INFF __builtin_huge_valf()

// ---------------- workspace zero-init (ws is re-poisoned 0xAA every call) ---
__global__ void init_ws(float* __restrict__ arrs, int n, double* __restrict__ contra) {
    int i = blockIdx.x * blockDim.x + threadIdx.x;
    if (i == 0) *contra = 0.0;
    if (i < n) arrs[i] = 0.0f;
}

// ---------------- per-sample min-distance + segment sums --------------------
// One wave (64 lanes) per sample. Lane handles classes lane, lane+64, ...
// Memory-bound: reads B*C*P*4 bytes once, coalesced-ish (contiguous 40B/lane).
__global__ __launch_bounds__(256) void sample_kernel(
    const float* __restrict__ sims, const int* __restrict__ labels,
    const int* __restrict__ pidx,
    float* __restrict__ cls_sum, float* __restrict__ cls_n,
    float* __restrict__ sep_sum, int B, int C, int P) {
    int gid = blockIdx.x * blockDim.x + threadIdx.x;
    int w = gid >> 6;
    int lane = threadIdx.x & 63;
    if (w >= B) return;
    int label = labels[w];
    const float* base = sims + (size_t)w * C * P;
    float own = INFF, other = INFF;
    for (int cc = 0; cc < C; cc += 64) {
        int c = cc + lane;
        if (c < C) {
            int cnt = pidx[2 * c + 1] - pidx[2 * c];
            const float* cb = base + (size_t)c * P;
            float m = INFF;
            if ((P & 1) == 0) {
                // (b*C+c)*P*4 bytes is 8-aligned when P even -> float2 ok
                const float2* cb2 = reinterpret_cast<const float2*>(cb);
                for (int p2 = 0; p2 < (P >> 1); ++p2) {
                    float2 v = cb2[p2];
                    int p = p2 * 2;
                    float d0 = (p < cnt) ? (1.0f - v.x) : INFF;
                    float d1 = (p + 1 < cnt) ? (1.0f - v.y) : INFF;
                    m = fminf(m, fminf(d0, d1));
                }
            } else {
                for (int p = 0; p < P; ++p) {
                    float v = cb[p];
                    m = fminf(m, (p < cnt) ? (1.0f - v) : INFF);
                }
            }
            if (c == label) own = m;
            else other = fminf(other, m);
        }
    }
#pragma unroll
    for (int off = 32; off > 0; off >>= 1) {
        own = fminf(own, __shfl_xor(own, off));
        other = fminf(other, __shfl_xor(other, off));
    }
    if (lane == 0) {
        unsafeAtomicAdd(&cls_sum[label], own);
        unsafeAtomicAdd(&cls_n[label], 1.0f);
        unsafeAtomicAdd(&sep_sum[label], fmaxf(MARGIN_C - other, 0.0f));
    }
}

// ---------------- per-prototype inverse norm + class id ---------------------
// One wave per prototype row.
__global__ __launch_bounds__(256) void norm_kernel(
    const float* __restrict__ protos, const int* __restrict__ pidx,
    float* __restrict__ inv_norm, int* __restrict__ pclass,
    int T, int D, int C) {
    int gid = blockIdx.x * blockDim.x + threadIdx.x;
    int w = gid >> 6;
    int lane = threadIdx.x & 63;
    if (w >= T) return;
    const float* row = protos + (size_t)w * D;
    float ss = 0.0f;
    for (int k = lane; k < D; k += 64) {
        float v = row[k];
        ss += v * v;
    }
#pragma unroll
    for (int off = 32; off > 0; off >>= 1) ss += __shfl_xor(ss, off);
    if (lane == 0) {
        float nrm = sqrtf(ss);
        inv_norm[w] = 1.0f / fmaxf(nrm, 1e-12f);
        // searchsorted(starts, w, 'right') - 1
        int lo = 0, hi = C;
        while (lo < hi) {
            int mid = (lo + hi) >> 1;
            if (pidx[2 * mid] <= w) lo = mid + 1;
            else hi = mid;
        }
        pclass[w] = lo - 1;
    }
}

// ---------------- pairwise cosine-sim tiles + accumulation ------------------
// 64x64 output tile per 256-thread block; 4x4 register blocking; K-chunks of
// 32 staged in LDS with normalization folded into the tile load.
#define BLKT 64
#define KC 32
__global__ __launch_bounds__(256) void sim_kernel(
    const float* __restrict__ protos, const float* __restrict__ inv_norm,
    const int* __restrict__ pclass, const int* __restrict__ vmask,
    float* __restrict__ cls_pair, double* __restrict__ contra, int T, int D) {
    __shared__ float As[KC][BLKT];
    __shared__ float Bs[KC][BLKT];
    __shared__ double red[256];
    int t = threadIdx.x;
    int tx = t & 15, ty = t >> 4;
    int i0 = blockIdx.y * BLKT, j0 = blockIdx.x * BLKT;
    float acc[4][4] = {};
    for (int k0 = 0; k0 < D; k0 += KC) {
#pragma unroll
        for (int r = 0; r < (BLKT * KC) / 256; ++r) {
            int idx = t + r * 256;
            int kk = idx & (KC - 1);
            int ii = idx >> 5;  // log2(KC)
            int gk = k0 + kk;
            int gi = i0 + ii;
            As[kk][ii] = (gi < T && gk < D) ? protos[(size_t)gi * D + gk] * inv_norm[gi] : 0.0f;
            int gj = j0 + ii;
            Bs[kk][ii] = (gj < T && gk < D) ? protos[(size_t)gj * D + gk] * inv_norm[gj] : 0.0f;
        }
        __syncthreads();
#pragma unroll
        for (int kk = 0; kk < KC; ++kk) {
            float4 a = *reinterpret_cast<const float4*>(&As[kk][ty * 4]);
            float4 b = *reinterpret_cast<const float4*>(&Bs[kk][tx * 4]);
            float av[4] = {a.x, a.y, a.z, a.w};
            float bv[4] = {b.x, b.y, b.z, b.w};
#pragma unroll
            for (int e = 0; e < 4; ++e)
#pragma unroll
                for (int f = 0; f < 4; ++f) acc[e][f] += av[e] * bv[f];
        }
        __syncthreads();
    }
    // epilogue: contrastive sum (block-reduced, double atomic) + div rel sums
    float local = 0.0f;
    int iBase = i0 + ty * 4, jBase = j0 + tx * 4;
#pragma unroll
    for (int e = 0; e < 4; ++e) {
        int i = iBase + e;
        if (i >= T) continue;
        int ci = pclass[i];
        bool vi = vmask[i] != 0;
#pragma unroll
        for (int f = 0; f < 4; ++f) {
            int j = jBase + f;
            if (j >= T || j == i) continue;
            float s = acc[e][f];
            if (vi && (vmask[j] != 0)) local += s;
            if (ci >= 0 && ci == pclass[j]) {
                float rel = s - 0.5f;
                if (rel > 0.0f) unsafeAtomicAdd(&cls_pair[ci], rel);
            }
        }
    }
    red[t] = (double)local;
    __syncthreads();
#pragma unroll
    for (int s2 = 128; s2 > 0; s2 >>= 1) {
        if (t < s2) red[t] += red[t + s2];
        __syncthreads();
    }
    if (t == 0) unsafeAtomicAdd(contra, red[0]);
}

// ---------------- combine the four losses -----------------------------------
__global__ void finalize_kernel(
    const float* __restrict__ cls_sum, const float* __restrict__ cls_n,
    const float* __restrict__ sep_sum, const float* __restrict__ cls_pair,
    const double* __restrict__ contra, const int* __restrict__ pidx,
    const int* __restrict__ vmask, float* __restrict__ out, int C, int T) {
    int lane = threadIdx.x & 63;
    float cl = 0.0f, sp = 0.0f, dv = 0.0f;
    int nval = 0, ndv = 0, V = 0;
    for (int c = lane; c < C; c += 64) {
        float n = cls_n[c];
        if (n > 0.0f) {
            nval += 1;
            float nm = fmaxf(n, 1.0f);
            float w = 1.0f / sqrtf(n + 1e-6f);
            cl += w * (cls_sum[c] / nm);
            sp += sep_sum[c] / nm;
        }
        int cnt = pidx[2 * c + 1] - pidx[2 * c];
        if (cnt > 1) {
            ndv += 1;
            float np = (float)(cnt * (cnt - 1));
            dv += cls_pair[c] / fmaxf(np, 1.0f);
        }
    }
    for (int tt = lane; tt < T; tt += 64) V += (vmask[tt] != 0) ? 1 : 0;
#pragma unroll
    for (int off = 32; off > 0; off >>= 1) {
        cl += __shfl_xor(cl, off);
        sp += __shfl_xor(sp, off);
        dv += __shfl_xor(dv, off);
        nval += __shfl_xor(nval, off);
        ndv += __shfl_xor(ndv, off);
        V += __shfl_xor(V, off);
    }
    if (lane == 0) {
        int nv = nval > 1 ? nval : 1;
        int nd = ndv > 1 ? ndv : 1;
        float cluster = cl / (float)nv * CLST_SCALE;
        float sep = sp / (float)nv * SEP_SCALE;
        float div = dv / (float)nd * DIV_SCALE;
        long long nvp = (long long)V * (long long)V - (long long)V;
        if (nvp < 1) nvp = 1;
        float contrastive = (float)(*contra / (double)nvp) * CONTRASTIVE_SCALE;
        out[0] = cluster;
        out[1] = sep;
        out[2] = div;
        out[3] = contrastive;
        out[4] = cluster + sep + div + contrastive;
    }
}

extern "C" void kernel_launch(void* const* d_in, const int* in_sizes, int n_in,
                              void* d_out, int out_size, void* d_ws, size_t ws_size,
                              hipStream_t stream) {
    const float* sims = (const float*)d_in[0];
    const int* labels = (const int*)d_in[1];
    const float* protos = (const float*)d_in[2];
    const int* pidx = (const int*)d_in[3];
    const int* vmask = (const int*)d_in[4];
    float* out = (float*)d_out;

    int B = in_sizes[1];
    int C = in_sizes[3] / 2;
    int T = in_sizes[4];
    int D = in_sizes[2] / T;
    int P = in_sizes[0] / (B * C);

    // workspace layout (bytes): [0..8) contra double; [16..16+16C) 4 float
    // arrays of C (cls_sum, cls_n, sep_sum, cls_pair); then inv_norm[T] f32;
    // then pclass[T] i32.  ~10 KB total.
    char* ws = (char*)d_ws;
    double* contra = (double*)ws;
    float* cls_sum = (float*)(ws + 16);
    float* cls_n = cls_sum + C;
    float* sep_sum = cls_n + C;
    float* cls_pair = sep_sum + C;
    float* inv_norm = cls_pair + C;
    int* pclass = (int*)(inv_norm + T);

    int nz = 4 * C;
    init_ws<<<dim3((nz + 255) / 256), dim3(256), 0, stream>>>(cls_sum, nz, contra);

    long long sthreads = (long long)B * 64;
    sample_kernel<<<dim3((unsigned)((sthreads + 255) / 256)), dim3(256), 0, stream>>>(
        sims, labels, pidx, cls_sum, cls_n, sep_sum, B, C, P);

    long long nthreads = (long long)T * 64;
    norm_kernel<<<dim3((unsigned)((nthreads + 255) / 256)), dim3(256), 0, stream>>>(
        protos, pidx, inv_norm, pclass, T, D, C);

    dim3 g((T + BLKT - 1) / BLKT, (T + BLKT - 1) / BLKT);
    sim_kernel<<<g, dim3(256), 0, stream>>>(protos, inv_norm, pclass, vmask,
                                            cls_pair, contra, T, D);

    finalize_kernel<<<dim3(1), dim3(64), 0, stream>>>(
        cls_sum, cls_n, sep_sum, cls_pair, contra, pidx, vmask, out, C, T);
}